// Round 1
// baseline (3411.731 us; speedup 1.0000x reference)
//
#include <hip/hip_runtime.h>
#include <cstdint>

#define K_CODES 8192
#define D_DIM   512
#define N_VEC   32768          // 16*2048
#define DECAY   0.99f
#define EPS_VQ  1e-5f
#define COMMIT  0.25f

// ---------------- output layout (float32, concatenated in return order) ---
// [0]                      vq_loss          (1)
// [1 .. 16777217)          z_q_out          (16777216)
// [16777217 .. 16809985)   codes_out        (32768, as float)
// [16809985 .. 21004289)   new_weight       (4194304)
// [21004289 .. 21012481)   new_cs           (8192)
// [21012481 .. 25206785)   new_ema_w        (4194304)

// ---------------- K1: wsq[k] = sum_d w[k][d]^2 ----------------------------
__global__ __launch_bounds__(256)
void wsq_kernel(const float* __restrict__ w, float* __restrict__ wsq) {
    int wave = threadIdx.x >> 6, lane = threadIdx.x & 63;
    int row  = blockIdx.x * 4 + wave;
    const float4* p = (const float4*)(w + (size_t)row * D_DIM);
    float4 a = p[lane], b = p[lane + 64];
    float s = a.x*a.x + a.y*a.y + a.z*a.z + a.w*a.w
            + b.x*b.x + b.y*b.y + b.z*b.z + b.w*b.w;
    #pragma unroll
    for (int off = 32; off; off >>= 1) s += __shfl_down(s, off);
    if (lane == 0) wsq[row] = s;
}

// ---------------- K2: fused distance GEMM + argmin ------------------------
// dist(n,k) ~ wsq[k] - 2*dot(z_n, w_k)   (||z||^2 dropped: row-constant)
// 128x128 tile per block, 8x8 microtile per thread, D staged in BD=32 chunks.
#define BN 128
#define BK 128
#define BD 32
#define LPAD 4

__global__ __launch_bounds__(256, 4)
void dist_argmin_kernel(const float* __restrict__ z, const float* __restrict__ w,
                        const float* __restrict__ wsq,
                        unsigned long long* __restrict__ best) {
    __shared__ float zs [BD][BN + LPAD];
    __shared__ float wls[BD][BK + LPAD];

    const int n0 = blockIdx.x * BN;
    const int k0 = blockIdx.y * BK;
    const int t  = threadIdx.x;
    const int tx = t & 15, ty = t >> 4;

    float acc[8][8];
    #pragma unroll
    for (int i = 0; i < 8; ++i)
        #pragma unroll
        for (int j = 0; j < 8; ++j) acc[i][j] = 0.0f;

    const int r  = t >> 3;   // 0..31
    const int cq = t & 7;    // 0..7 (float4 column quad)

    for (int d0 = 0; d0 < D_DIM; d0 += BD) {
        #pragma unroll
        for (int it = 0; it < 4; ++it) {
            int rr = r + 32 * it;
            float4 v = *(const float4*)(z + (size_t)(n0 + rr) * D_DIM + d0 + cq * 4);
            zs[cq*4+0][rr] = v.x; zs[cq*4+1][rr] = v.y;
            zs[cq*4+2][rr] = v.z; zs[cq*4+3][rr] = v.w;
            float4 u = *(const float4*)(w + (size_t)(k0 + rr) * D_DIM + d0 + cq * 4);
            wls[cq*4+0][rr] = u.x; wls[cq*4+1][rr] = u.y;
            wls[cq*4+2][rr] = u.z; wls[cq*4+3][rr] = u.w;
        }
        __syncthreads();

        for (int d = 0; d < BD; ++d) {
            float a[8], b[8];
            #pragma unroll
            for (int i = 0; i < 8; ++i) a[i] = zs[d][ty * 8 + i];
            #pragma unroll
            for (int j = 0; j < 4; ++j) {
                b[j]     = wls[d][tx * 4 + j];
                b[4 + j] = wls[d][64 + tx * 4 + j];
            }
            #pragma unroll
            for (int i = 0; i < 8; ++i)
                #pragma unroll
                for (int j = 0; j < 8; ++j)
                    acc[i][j] += a[i] * b[j];
        }
        __syncthreads();
    }

    // epilogue: dist + per-row argmin; cols owned by thread are ascending.
    #pragma unroll
    for (int i = 0; i < 8; ++i) {
        float bv = INFINITY; int bi = 0;
        #pragma unroll
        for (int j = 0; j < 8; ++j) {
            int col = (j < 4) ? (tx * 4 + j) : (64 + tx * 4 + (j - 4));
            float dist = wsq[k0 + col] - 2.0f * acc[i][j];
            if (dist < bv) { bv = dist; bi = k0 + col; }
        }
        // reduce across the 16 lanes (tx) sharing this row; idx-tiebreak = first min
        #pragma unroll
        for (int m = 8; m; m >>= 1) {
            float ov = __shfl_xor(bv, m);
            int   oi = __shfl_xor(bi, m);
            if (ov < bv || (ov == bv && oi < bi)) { bv = ov; bi = oi; }
        }
        if (tx == 0) {
            unsigned u = __float_as_uint(bv);
            u = (u & 0x80000000u) ? ~u : (u | 0x80000000u);  // order-preserving map
            unsigned long long key = ((unsigned long long)u << 32) | (unsigned)bi;
            atomicMin(&best[n0 + ty * 8 + i], key);
        }
    }
}

// ---------------- K3: decode codes, counts + dw scatter -------------------
__global__ __launch_bounds__(256)
void scatter_kernel(const unsigned long long* __restrict__ best,
                    const float* __restrict__ z,
                    int* __restrict__ codes_i, float* __restrict__ codes_f,
                    float* __restrict__ cnt_acc,   // d_out new_cs region (zeroed)
                    float* __restrict__ dw_acc) {  // d_out new_ema_w region (zeroed)
    int row = blockIdx.x * 8 + (threadIdx.x >> 5);
    int c   = threadIdx.x & 31;
    int code = (int)(best[row] & 0xFFFFFFFFull);
    if (c == 0) {
        codes_i[row] = code;
        codes_f[row] = (float)code;
        atomicAdd(&cnt_acc[code], 1.0f);
    }
    const float* zr = z + (size_t)row * D_DIM;
    float* dr = dw_acc + (size_t)code * D_DIM;
    #pragma unroll
    for (int d = c; d < D_DIM; d += 32) atomicAdd(&dr[d], zr[d]);
}

// ---------------- K4: new_cs (in-place) + nsum reduction ------------------
__global__ __launch_bounds__(256)
void cs_kernel(const float* __restrict__ ema_cs, float* __restrict__ cs_out,
               float* __restrict__ nsum) {
    __shared__ float wsum[4];
    int i = blockIdx.x * 256 + threadIdx.x;
    float v = ema_cs[i] * DECAY + (1.0f - DECAY) * cs_out[i];
    cs_out[i] = v;
    float s = v;
    #pragma unroll
    for (int off = 32; off; off >>= 1) s += __shfl_down(s, off);
    int lane = threadIdx.x & 63, wid = threadIdx.x >> 6;
    if (lane == 0) wsum[wid] = s;
    __syncthreads();
    if (threadIdx.x == 0)
        atomicAdd(nsum, wsum[0] + wsum[1] + wsum[2] + wsum[3]);
}

// ---------------- K5: new_ema_w (in-place) + new_weight -------------------
__global__ __launch_bounds__(256)
void weight_kernel(const float* __restrict__ ema_w, const float* __restrict__ cs,
                   const float* __restrict__ nsum_p,
                   float* __restrict__ emaw_out, float* __restrict__ w_out) {
    int i = blockIdx.x * 256 + threadIdx.x;   // < 4194304
    float dw = emaw_out[i];
    float ne = ema_w[i] * DECAY + (1.0f - DECAY) * dw;
    emaw_out[i] = ne;
    int k = i >> 9;
    float n = *nsum_p;
    float csize = (cs[k] + EPS_VQ) / (n + (float)K_CODES * EPS_VQ) * n;
    w_out[i] = ne / csize;
}

// ---------------- K6: z_q gather + loss partial sums ----------------------
__global__ __launch_bounds__(256)
void gather_loss_kernel(const float* __restrict__ z, const int* __restrict__ codes,
                        const float* __restrict__ w, float* __restrict__ zq,
                        float* __restrict__ loss_acc) {
    __shared__ float wsum[4];
    int row  = blockIdx.x * 4 + (threadIdx.x >> 6);
    int lane = threadIdx.x & 63;
    int code = codes[row];
    const float* zr = z + (size_t)row * D_DIM;
    const float* wr = w + (size_t)code * D_DIM;
    float s = 0.0f;
    #pragma unroll
    for (int d = lane; d < D_DIM; d += 64) {
        float q = wr[d];
        float diff = q - zr[d];
        s += diff * diff;
        zq[(size_t)row * D_DIM + d] = q;
    }
    #pragma unroll
    for (int off = 32; off; off >>= 1) s += __shfl_down(s, off);
    int wid = threadIdx.x >> 6;
    if (lane == 0) wsum[wid] = s;
    __syncthreads();
    if (threadIdx.x == 0)
        atomicAdd(loss_acc, wsum[0] + wsum[1] + wsum[2] + wsum[3]);
}

__global__ void finalize_kernel(const float* __restrict__ loss_acc,
                                float* __restrict__ out0) {
    *out0 = COMMIT * (*loss_acc) / 16777216.0f;
}

// ---------------- launch --------------------------------------------------
extern "C" void kernel_launch(void* const* d_in, const int* in_sizes, int n_in,
                              void* d_out, int out_size, void* d_ws, size_t ws_size,
                              hipStream_t stream) {
    const float* z       = (const float*)d_in[0];
    const float* weight  = (const float*)d_in[1];
    const float* ema_cs  = (const float*)d_in[2];
    const float* ema_w   = (const float*)d_in[3];

    float* out       = (float*)d_out;
    float* out_loss  = out;
    float* out_zq    = out + 1;
    float* out_codes = out + 16777217;
    float* out_w     = out + 16809985;
    float* out_cs    = out + 21004289;
    float* out_emaw  = out + 21012481;

    char* ws = (char*)d_ws;
    float*              wsq      = (float*)ws;                            // 32 KB
    unsigned long long* best     = (unsigned long long*)(ws + 8192*4);    // 256 KB
    int*                codes_i  = (int*)(ws + 8192*4 + 32768*8);         // 128 KB
    float*              nsum     = (float*)(ws + 8192*4 + 32768*8 + 32768*4);
    float*              loss_acc = nsum + 1;

    hipMemsetAsync(best, 0xFF, 32768 * 8, stream);          // key = ULLONG_MAX
    hipMemsetAsync(nsum, 0, 8, stream);                      // nsum + loss_acc
    hipMemsetAsync(out_cs, 0, 8192 * 4, stream);             // counts accumulator
    hipMemsetAsync(out_emaw, 0, (size_t)4194304 * 4, stream);// dw accumulator

    wsq_kernel<<<2048, 256, 0, stream>>>(weight, wsq);
    dim3 g2(N_VEC / BN, K_CODES / BK);                       // 256 x 64
    dist_argmin_kernel<<<g2, 256, 0, stream>>>(z, weight, wsq, best);
    scatter_kernel<<<N_VEC / 8, 256, 0, stream>>>(best, z, codes_i, out_codes,
                                                  out_cs, out_emaw);
    cs_kernel<<<K_CODES / 256, 256, 0, stream>>>(ema_cs, out_cs, nsum);
    weight_kernel<<<4194304 / 256, 256, 0, stream>>>(ema_w, out_cs, nsum,
                                                     out_emaw, out_w);
    gather_loss_kernel<<<N_VEC / 4, 256, 0, stream>>>(z, codes_i, out_w,
                                                      out_zq, loss_acc);
    finalize_kernel<<<1, 1, 0, stream>>>(loss_acc, out_loss);
}

// Round 2
// 1789.550 us; speedup vs baseline: 1.9065x; 1.9065x over previous
//
#include <hip/hip_runtime.h>
#include <cstdint>

#define K_CODES 8192
#define D_DIM   512
#define N_VEC   32768          // 16*2048
#define DECAY   0.99f
#define EPS_VQ  1e-5f
#define COMMIT  0.25f

typedef _Float16 half_t;
typedef _Float16 half8 __attribute__((ext_vector_type(8)));
typedef _Float16 half4 __attribute__((ext_vector_type(4)));
typedef float    f32x4 __attribute__((ext_vector_type(4)));

// async global->LDS DMA, 16B per lane; LDS dest must be linear in lane order
#define GL2L(g, l)                                                              \
    __builtin_amdgcn_global_load_lds(                                           \
        (const __attribute__((address_space(1))) unsigned int*)(g),             \
        (__attribute__((address_space(3))) unsigned int*)(l), 16, 0, 0)

// ---------------- output layout (float32, concatenated in return order) ---
// [0]                      vq_loss          (1)
// [1 .. 16777217)          z_q_out          (16777216)
// [16777217 .. 16809985)   codes_out        (32768, as float)
// [16809985 .. 21004289)   new_weight       (4194304)
// [21004289 .. 21012481)   new_cs           (8192)
// [21012481 .. 25206785)   new_ema_w        (4194304)
//
// Scratch (split-f16 operands) lives in d_out floats [4 .. 20971524):
//   A_hi [32768x512] f16, A_lo, B_hi [8192x512] f16, B_lo — all consumed by
//   dist_mfma_kernel BEFORE any of those output regions are written.

// ---------------- K0: fp32 -> (hi,lo) f16 split ---------------------------
__global__ __launch_bounds__(256)
void conv_split_kernel(const float* __restrict__ x, half_t* __restrict__ hi,
                       half_t* __restrict__ lo) {
    int i = blockIdx.x * 256 + threadIdx.x;          // float4 index
    float4 v = ((const float4*)x)[i];
    float vv[4] = {v.x, v.y, v.z, v.w};
    half4 h, l;
    #pragma unroll
    for (int j = 0; j < 4; ++j) {
        _Float16 hh = (_Float16)vv[j];
        h[j] = hh;
        l[j] = (_Float16)(vv[j] - (float)hh);        // exact residual (Sterbenz)
    }
    *(half4*)(hi + (size_t)i * 4) = h;
    *(half4*)(lo + (size_t)i * 4) = l;
}

// ---------------- K1: wsq[k] = sum_d w[k][d]^2 (fp32) ---------------------
__global__ __launch_bounds__(256)
void wsq_kernel(const float* __restrict__ w, float* __restrict__ wsq) {
    int wave = threadIdx.x >> 6, lane = threadIdx.x & 63;
    int row  = blockIdx.x * 4 + wave;
    const float4* p = (const float4*)(w + (size_t)row * D_DIM);
    float4 a = p[lane], b = p[lane + 64];
    float s = a.x*a.x + a.y*a.y + a.z*a.z + a.w*a.w
            + b.x*b.x + b.y*b.y + b.z*b.z + b.w*b.w;
    #pragma unroll
    for (int off = 32; off; off >>= 1) s += __shfl_down(s, off);
    if (lane == 0) wsq[row] = s;
}

// ---------------- K2: MFMA dist GEMM + fused argmin -----------------------
// dist(n,k) ~ wsq[k] - 2*dot(z_n,w_k); dot via 3-term split-f16 MFMA,
// K-concat segments: c<8:(Ahi,Bhi)  8<=c<16:(Ahi,Blo)  c>=16:(Alo,Bhi).
// 128x128 tile, 4 waves as 2x2 of 64x64, 16x16x32_f16 MFMA, BK=64 halves.
__global__ __launch_bounds__(256)
void dist_mfma_kernel(const half_t* __restrict__ A_hi, const half_t* __restrict__ A_lo,
                      const half_t* __restrict__ B_hi, const half_t* __restrict__ B_lo,
                      const float* __restrict__ wsq,
                      unsigned long long* __restrict__ best) {
    __shared__ __align__(16) half_t As[128 * 64];
    __shared__ __align__(16) half_t Bs[128 * 64];

    const int k0 = blockIdx.x * 128;      // codes
    const int n0 = blockIdx.y * 128;      // z rows
    const int t    = threadIdx.x;
    const int lane = t & 63;
    const int wave = t >> 6;
    const int wm = (wave >> 1) * 64;
    const int wn = (wave & 1) * 64;
    const int l15 = lane & 15;
    const int q   = lane >> 4;

    f32x4 acc[4][4];
    #pragma unroll
    for (int mi = 0; mi < 4; ++mi)
        #pragma unroll
        for (int ni = 0; ni < 4; ++ni) acc[mi][ni] = (f32x4)0.0f;

    for (int c = 0; c < 24; ++c) {
        const half_t* Aseg = (c < 16) ? A_hi : A_lo;
        const half_t* Bseg = (c >= 8 && c < 16) ? B_lo : B_hi;
        const int koff = (c & 7) * 64;
        #pragma unroll
        for (int it = 0; it < 4; ++it) {
            int idx  = t + 256 * it;            // 16B chunk id, lane-linear
            int row  = idx >> 3;                // 0..127
            int col8 = (idx & 7) ^ (row & 7);   // XOR-swizzled global column
            GL2L(Aseg + (size_t)(n0 + row) * D_DIM + koff + col8 * 8, As + idx * 8);
            GL2L(Bseg + (size_t)(k0 + row) * D_DIM + koff + col8 * 8, Bs + idx * 8);
        }
        __syncthreads();
        #pragma unroll
        for (int kk = 0; kk < 2; ++kk) {
            half8 af[4], bf[4];
            const int cpos = ((kk * 4 + q) ^ (lane & 7)) * 8;   // de-swizzle
            #pragma unroll
            for (int mi = 0; mi < 4; ++mi)
                af[mi] = *(const half8*)&As[(wm + mi * 16 + l15) * 64 + cpos];
            #pragma unroll
            for (int ni = 0; ni < 4; ++ni)
                bf[ni] = *(const half8*)&Bs[(wn + ni * 16 + l15) * 64 + cpos];
            #pragma unroll
            for (int mi = 0; mi < 4; ++mi)
                #pragma unroll
                for (int ni = 0; ni < 4; ++ni)
                    acc[mi][ni] = __builtin_amdgcn_mfma_f32_16x16x32_f16(
                        af[mi], bf[ni], acc[mi][ni], 0, 0, 0);
        }
        __syncthreads();
    }

    // epilogue: C/D layout col=lane&15, row=q*4+r (m89-verified)
    #pragma unroll
    for (int mi = 0; mi < 4; ++mi) {
        #pragma unroll
        for (int r = 0; r < 4; ++r) {
            int grow = n0 + wm + mi * 16 + q * 4 + r;
            float bv = INFINITY; int bi = 0x7FFFFFFF;
            #pragma unroll
            for (int ni = 0; ni < 4; ++ni) {           // ni ascending => cols ascending
                int col = k0 + wn + ni * 16 + l15;
                float d = wsq[col] - 2.0f * acc[mi][ni][r];
                if (d < bv) { bv = d; bi = col; }
            }
            #pragma unroll
            for (int m = 1; m <= 8; m <<= 1) {         // reduce 16-lane col group
                float ov = __shfl_xor(bv, m);
                int   oi = __shfl_xor(bi, m);
                if (ov < bv || (ov == bv && oi < bi)) { bv = ov; bi = oi; }
            }
            if (l15 == 0) {
                unsigned u = __float_as_uint(bv);
                u = (u & 0x80000000u) ? ~u : (u | 0x80000000u);
                unsigned long long key = ((unsigned long long)u << 32) | (unsigned)bi;
                atomicMin(&best[grow], key);
            }
        }
    }
}

// ---------------- K3: decode codes, counts + dw scatter -------------------
__global__ __launch_bounds__(256)
void scatter_kernel(const unsigned long long* __restrict__ best,
                    const float* __restrict__ z,
                    int* __restrict__ codes_i, float* __restrict__ codes_f,
                    float* __restrict__ cnt_acc, float* __restrict__ dw_acc) {
    int row = blockIdx.x * 8 + (threadIdx.x >> 5);
    int c   = threadIdx.x & 31;
    int code = (int)(best[row] & 0xFFFFFFFFull);
    if (c == 0) {
        codes_i[row] = code;
        codes_f[row] = (float)code;
        atomicAdd(&cnt_acc[code], 1.0f);
    }
    const float* zr = z + (size_t)row * D_DIM;
    float* dr = dw_acc + (size_t)code * D_DIM;
    #pragma unroll
    for (int d = c; d < D_DIM; d += 32) atomicAdd(&dr[d], zr[d]);
}

// ---------------- K4: new_cs (in-place) + nsum ----------------------------
__global__ __launch_bounds__(256)
void cs_kernel(const float* __restrict__ ema_cs, float* __restrict__ cs_out,
               float* __restrict__ nsum) {
    __shared__ float wsum[4];
    int i = blockIdx.x * 256 + threadIdx.x;
    float v = ema_cs[i] * DECAY + (1.0f - DECAY) * cs_out[i];
    cs_out[i] = v;
    float s = v;
    #pragma unroll
    for (int off = 32; off; off >>= 1) s += __shfl_down(s, off);
    int lane = threadIdx.x & 63, wid = threadIdx.x >> 6;
    if (lane == 0) wsum[wid] = s;
    __syncthreads();
    if (threadIdx.x == 0)
        atomicAdd(nsum, wsum[0] + wsum[1] + wsum[2] + wsum[3]);
}

// ---------------- K5: new_ema_w (in-place) + new_weight -------------------
__global__ __launch_bounds__(256)
void weight_kernel(const float* __restrict__ ema_w, const float* __restrict__ cs,
                   const float* __restrict__ nsum_p,
                   float* __restrict__ emaw_out, float* __restrict__ w_out) {
    int i = blockIdx.x * 256 + threadIdx.x;
    float dw = emaw_out[i];
    float ne = ema_w[i] * DECAY + (1.0f - DECAY) * dw;
    emaw_out[i] = ne;
    int k = i >> 9;
    float n = *nsum_p;
    float csize = (cs[k] + EPS_VQ) / (n + (float)K_CODES * EPS_VQ) * n;
    w_out[i] = ne / csize;
}

// ---------------- K6: z_q gather + loss -----------------------------------
__global__ __launch_bounds__(256)
void gather_loss_kernel(const float* __restrict__ z, const int* __restrict__ codes,
                        const float* __restrict__ w, float* __restrict__ zq,
                        float* __restrict__ loss_acc) {
    __shared__ float wsum[4];
    int row  = blockIdx.x * 4 + (threadIdx.x >> 6);
    int lane = threadIdx.x & 63;
    int code = codes[row];
    const float* zr = z + (size_t)row * D_DIM;
    const float* wr = w + (size_t)code * D_DIM;
    float s = 0.0f;
    #pragma unroll
    for (int d = lane; d < D_DIM; d += 64) {
        float qv = wr[d];
        float diff = qv - zr[d];
        s += diff * diff;
        zq[(size_t)row * D_DIM + d] = qv;
    }
    #pragma unroll
    for (int off = 32; off; off >>= 1) s += __shfl_down(s, off);
    int wid = threadIdx.x >> 6;
    if (lane == 0) wsum[wid] = s;
    __syncthreads();
    if (threadIdx.x == 0)
        atomicAdd(loss_acc, wsum[0] + wsum[1] + wsum[2] + wsum[3]);
}

__global__ void finalize_kernel(const float* __restrict__ loss_acc,
                                float* __restrict__ out0) {
    *out0 = COMMIT * (*loss_acc) / 16777216.0f;
}

// ---------------- launch --------------------------------------------------
extern "C" void kernel_launch(void* const* d_in, const int* in_sizes, int n_in,
                              void* d_out, int out_size, void* d_ws, size_t ws_size,
                              hipStream_t stream) {
    const float* z      = (const float*)d_in[0];
    const float* weight = (const float*)d_in[1];
    const float* ema_cs = (const float*)d_in[2];
    const float* ema_w  = (const float*)d_in[3];

    float* out       = (float*)d_out;
    float* out_loss  = out;
    float* out_zq    = out + 1;
    float* out_codes = out + 16777217;
    float* out_w     = out + 16809985;
    float* out_cs    = out + 21004289;
    float* out_emaw  = out + 21012481;

    // split-f16 scratch inside d_out (consumed before those regions are written)
    half_t* A_hi = (half_t*)(out + 4);                       // 16B-aligned
    half_t* A_lo = A_hi + (size_t)N_VEC * D_DIM;
    half_t* B_hi = A_lo + (size_t)N_VEC * D_DIM;
    half_t* B_lo = B_hi + (size_t)K_CODES * D_DIM;

    char* ws = (char*)d_ws;
    float*              wsq      = (float*)ws;                           // 32 KB
    unsigned long long* best     = (unsigned long long*)(ws + 8192*4);   // 256 KB
    int*                codes_i  = (int*)(ws + 8192*4 + 32768*8);        // 128 KB
    float*              nsum     = (float*)(ws + 8192*4 + 32768*8 + 32768*4);
    float*              loss_acc = nsum + 1;

    hipMemsetAsync(best, 0xFF, 32768 * 8, stream);            // ULLONG_MAX keys
    hipMemsetAsync(nsum, 0, 8, stream);                       // nsum + loss_acc
    hipMemsetAsync(out_cs, 0, 8192 * 4, stream);              // counts acc
    hipMemsetAsync(out_emaw, 0, (size_t)4194304 * 4, stream); // dw acc

    conv_split_kernel<<<N_VEC * D_DIM / 4 / 256, 256, 0, stream>>>(z, A_hi, A_lo);
    conv_split_kernel<<<K_CODES * D_DIM / 4 / 256, 256, 0, stream>>>(weight, B_hi, B_lo);
    wsq_kernel<<<K_CODES / 4, 256, 0, stream>>>(weight, wsq);

    dim3 g2(K_CODES / 128, N_VEC / 128);                      // 64 x 256
    dist_mfma_kernel<<<g2, 256, 0, stream>>>(A_hi, A_lo, B_hi, B_lo, wsq, best);

    scatter_kernel<<<N_VEC / 8, 256, 0, stream>>>(best, z, codes_i, out_codes,
                                                  out_cs, out_emaw);
    cs_kernel<<<K_CODES / 256, 256, 0, stream>>>(ema_cs, out_cs, nsum);
    weight_kernel<<<4194304 / 256, 256, 0, stream>>>(ema_w, out_cs, nsum,
                                                     out_emaw, out_w);
    gather_loss_kernel<<<N_VEC / 4, 256, 0, stream>>>(z, codes_i, out_w,
                                                      out_zq, loss_acc);
    finalize_kernel<<<1, 1, 0, stream>>>(loss_acc, out_loss);
}